// Round 17
// baseline (297.085 us; speedup 1.0000x reference)
//
#include <hip/hip_runtime.h>

#define T_   91
#define D_   256
#define H_   4
#define DH_  64
#define NA_  128
#define NRG_ 1024
#define KEXP_ 4

typedef float f32x4 __attribute__((ext_vector_type(4)));
typedef short bf16x8 __attribute__((ext_vector_type(8)));

static constexpr float P_EPS = 1.3877787807814457e-17f;  // 2^-56, exact in bf16

__device__ inline ushort f2bf(float f) {
    union { float f; unsigned u; } v; v.f = f;
    unsigned r = (v.u + 0x7fffu + ((v.u >> 16) & 1u)) >> 16;
    return (ushort)r;
}
__device__ inline unsigned pk2(float a, float b) {
    return (unsigned)f2bf(a) | ((unsigned)f2bf(b) << 16);
}
__device__ inline float bf2f(ushort b) {
    union { unsigned u; float f; } v; v.u = ((unsigned)b) << 16;
    return v.f;
}

#define LN_BLOCKS 2912    // NA*T/4 (agent rows only)
#define PM_BLOCKS 2912    // T*NA/4
#define PW_BLOCKS 3072    // 786432/256
#define KV_BLOCKS 2912    // 1456 tiles * 2 (K, V)

// ---------------------------------------------------------------------------
// prep_all: [0,LN) agent LN (wave/row) | [LN,LN+PM) pack_mask | rest prep_w
// ---------------------------------------------------------------------------
__global__ __launch_bounds__(256) void prep_all(
    const float* __restrict__ agent,
    const float* __restrict__ g, const float* __restrict__ b,
    const int* __restrict__ am, const int* __restrict__ pm,
    const int* __restrict__ vmk,
    const float* __restrict__ wk, const float* __restrict__ wv,
    const float* __restrict__ wq, const float* __restrict__ wy,
    const float* __restrict__ wf1, const float* __restrict__ wf2,
    ushort* __restrict__ agn, unsigned* __restrict__ cm,
    ushort* __restrict__ wkvt, ushort* __restrict__ wqt,
    ushort* __restrict__ wyt, ushort* __restrict__ wf1t,
    ushort* __restrict__ wf2t) {
    __shared__ int pmS[NRG_];
    int bid = blockIdx.x;
    if (bid < LN_BLOCKS) {
        int row = bid * 4 + (threadIdx.x >> 6);
        int lane = threadIdx.x & 63;
        f32x4 x = *(const f32x4*)(agent + (size_t)row * D_ + lane * 4);
        float s1 = x[0] + x[1] + x[2] + x[3];
        float s2 = x[0] * x[0] + x[1] * x[1] + x[2] * x[2] + x[3] * x[3];
#pragma unroll
        for (int off = 1; off < 64; off <<= 1) {
            s1 += __shfl_xor(s1, off);
            s2 += __shfl_xor(s2, off);
        }
        float mean = s1 * (1.0f / 256.0f);
        float var = s2 * (1.0f / 256.0f) - mean * mean;
        float rstd = rsqrtf(var + 1e-5f);
        f32x4 gv = *(const f32x4*)(g + lane * 4);
        f32x4 bv = *(const f32x4*)(b + lane * 4);
        float y0 = (x[0] - mean) * rstd * gv[0] + bv[0];
        float y1 = (x[1] - mean) * rstd * gv[1] + bv[1];
        float y2 = (x[2] - mean) * rstd * gv[2] + bv[2];
        float y3 = (x[3] - mean) * rstd * gv[3] + bv[3];
        *(uint2*)(agn + (size_t)row * D_ + lane * 4) =
            make_uint2(pk2(y0, y1), pk2(y2, y3));
    } else if (bid < LN_BLOCKS + PM_BLOCKS) {
        int base = (bid - LN_BLOCKS) * 4;
        int t = base / NA_;
        int w = threadIdx.x >> 6, lane = threadIdx.x & 63;
#pragma unroll
        for (int i = 0; i < 4; ++i)
            pmS[threadIdx.x + i * 256] = pm[(size_t)t * NRG_ + threadIdx.x + i * 256];
        __syncthreads();
        int idx = base + w;
        int a = idx & (NA_ - 1);
        int valid = vmk[t * NA_ + a];
        const int* amrow = am + (size_t)idx * NRG_;
#pragma unroll
        for (int c = 0; c < 16; ++c) {
            int r = c * 64 + lane;
            bool bit = valid && amrow[r] && pmS[r];
            unsigned long long msk = __ballot(bit);
            if (lane == 0) {
                cm[(size_t)idx * 32 + c * 2]     = (unsigned)msk;
                cm[(size_t)idx * 32 + c * 2 + 1] = (unsigned)(msk >> 32);
            }
        }
    } else {
        int idx = (bid - LN_BLOCKS - PM_BLOCKS) * 256 + threadIdx.x;
        if (idx < 131072) {
            const float* W = (idx < 65536) ? wk : wv;
            int li = idx & 65535;
            int n = li >> 8, k = li & 255;
            wkvt[idx] = f2bf(W[(size_t)k * 256 + n]);
        } else if (idx < 196608) {
            int li = idx - 131072;
            int n = li >> 8, k = li & 255;
            wqt[li] = f2bf(wq[(size_t)k * 256 + n]);
        } else if (idx < 262144) {
            int li = idx - 196608;
            int n = li >> 8, k = li & 255;
            wyt[li] = f2bf(wy[(size_t)k * 256 + n]);
        } else if (idx < 524288) {
            int li = idx - 262144;
            int n = li >> 8, k = li & 255;
            wf1t[li] = f2bf(wf1[(size_t)k * 1024 + n]);
        } else {
            int li = idx - 524288;
            int n = li >> 10, k = li & 1023;
            wf2t[li] = f2bf(wf2[(size_t)k * 256 + n]);
        }
    }
}

// ---------------------------------------------------------------------------
// KV + Q projection v10: round-11 exact structure; all large epilogue
// stores made NONTEMPORAL (nt flag) so the 297 MB write stream does not
// evict the L2-resident weight matrix / rg lines (write-allocate thrash).
// ---------------------------------------------------------------------------
__global__ __launch_bounds__(512) void gemm_kvq(
    const float* __restrict__ rgf, const ushort* __restrict__ agn,
    const float* __restrict__ lng, const float* __restrict__ lnb,
    const ushort* __restrict__ wkvt, const ushort* __restrict__ wqt,
    const float* __restrict__ bk, const float* __restrict__ bv,
    const float* __restrict__ bq, const float* __restrict__ qs,
    float* __restrict__ Kp, float* __restrict__ Vp, float* __restrict__ Qp,
    ushort* __restrict__ Kb, ushort* __restrict__ Vtb, ushort* __restrict__ Qb) {
    __shared__ ushort Asf[64][264];               // 33.8 KB (full 64x256 A tile)
    __shared__ ushort Bs[256][72];                // 36.9 KB

    int bid = blockIdx.x;
    bool isQ = bid >= KV_BLOCKS;
    int bxi = 0, t, rb = 0, a0 = 0;
    if (!isQ) {
        int sub = bid & 15, pid = bid >> 4;
        bxi = sub >> 3;
        int by = pid * 8 + (sub & 7);             // K/V pair differs by 8 in bid
        t = by >> 4; rb = (by & 15) << 6;
    } else {
        int qid = bid - KV_BLOCKS;                // 0..181
        t = qid >> 1; a0 = (qid & 1) << 6;
    }
    const ushort* Bt = isQ ? wqt : (wkvt + (size_t)(bxi << 8) * 256);

    int tid = threadIdx.x;
    int w = tid >> 6, lane = tid & 63;
    int wm = w >> 2, wn = w & 3;
    int l15 = lane & 15, l4 = lane >> 4;

    // ---- A tile into Asf (LN fused for rg path) ----
    if (!isQ) {
        int row = tid >> 3, l8 = tid & 7;
        const float* ap = rgf + ((size_t)(rb + row) * T_ + t) * 256;
        f32x4 xr[8];
#pragma unroll
        for (int c = 0; c < 8; ++c) xr[c] = *(const f32x4*)(ap + l8 * 4 + c * 32);
        float s1 = 0.0f, s2 = 0.0f;
#pragma unroll
        for (int c = 0; c < 8; ++c)
#pragma unroll
            for (int r = 0; r < 4; ++r) { s1 += xr[c][r]; s2 += xr[c][r] * xr[c][r]; }
#pragma unroll
        for (int off = 1; off < 8; off <<= 1) {
            s1 += __shfl_xor(s1, off);
            s2 += __shfl_xor(s2, off);
        }
        float mean = s1 * (1.0f / 256.0f);
        float var = s2 * (1.0f / 256.0f) - mean * mean;
        float rstd = rsqrtf(var + 1e-5f);
#pragma unroll
        for (int c = 0; c < 8; ++c) {
            int col = l8 * 4 + c * 32;
            f32x4 g4 = *(const f32x4*)(lng + col);
            f32x4 b4 = *(const f32x4*)(lnb + col);
            float y0 = (xr[c][0] - mean) * rstd * g4[0] + b4[0];
            float y1 = (xr[c][1] - mean) * rstd * g4[1] + b4[1];
            float y2 = (xr[c][2] - mean) * rstd * g4[2] + b4[2];
            float y3 = (xr[c][3] - mean) * rstd * g4[3] + b4[3];
            *(uint2*)&Asf[row][col] = make_uint2(pk2(y0, y1), pk2(y2, y3));
        }
    } else {
#pragma unroll
        for (int i2 = 0; i2 < 4; ++i2) {
            int chunk = tid + i2 * 512;
            int row = chunk >> 5, c8 = (chunk & 31) * 8;
            *(bf16x8*)&Asf[row][c8] =
                *(const bf16x8*)(agn + ((size_t)(a0 + row) * T_ + t) * 256 + c8);
        }
    }

    f32x4 acc[2][4];
#pragma unroll
    for (int i = 0; i < 2; ++i)
#pragma unroll
        for (int j = 0; j < 4; ++j)
#pragma unroll
            for (int r = 0; r < 4; ++r) acc[i][j][r] = 0.0f;

    for (int k0 = 0; k0 < 256; k0 += 64) {
#pragma unroll
        for (int it = 0; it < 4; ++it) {
            int li = tid + it * 512;
            int row = li >> 3, c8 = (li & 7) * 8;
            *(bf16x8*)&Bs[row][c8] =
                *(const bf16x8*)(Bt + (size_t)row * 256 + k0 + c8);
        }
        __syncthreads();
#pragma unroll
        for (int kk = 0; kk < 2; ++kk) {
            bf16x8 af[2], bfr[4];
#pragma unroll
            for (int i = 0; i < 2; ++i)
                af[i] = *(const bf16x8*)&Asf[wm * 32 + i * 16 + l15][k0 + kk * 32 + l4 * 8];
#pragma unroll
            for (int j = 0; j < 4; ++j)
                bfr[j] = *(const bf16x8*)&Bs[wn * 64 + j * 16 + l15][kk * 32 + l4 * 8];
#pragma unroll
            for (int i = 0; i < 2; ++i)
#pragma unroll
                for (int j = 0; j < 4; ++j)
                    acc[i][j] = __builtin_amdgcn_mfma_f32_16x16x32_bf16(
                        af[i], bfr[j], acc[i][j], 0, 0, 0);
        }
        __syncthreads();
    }

    // ---- direct epilogue: no barriers, nontemporal stores ----
#pragma unroll
    for (int i = 0; i < 2; ++i)
#pragma unroll
        for (int j = 0; j < 4; ++j) {
            int n = wn * 64 + j * 16 + l15;        // 0..255
            int h = n >> 6, d = n & 63;
            int m0 = wm * 32 + i * 16 + l4 * 4;    // tile row of reg 0
            float vv[4];
#pragma unroll
            for (int reg = 0; reg < 4; ++reg) {
                float bs = isQ ? bq[n] : (bxi ? bv[n] : bk[n]);
                float x = fmaxf(acc[i][j][reg] + bs, 0.0f);
                if (isQ) x *= qs[d];
                vv[reg] = x;
            }
            if (isQ) {
                size_t base = (((size_t)t * H_ + h) * NA_ + a0) * DH_ + d;
#pragma unroll
                for (int reg = 0; reg < 4; ++reg) {
                    __builtin_nontemporal_store(vv[reg],
                        Qp + base + (size_t)(m0 + reg) * DH_);
                    __builtin_nontemporal_store(f2bf(vv[reg] * 0.5f),
                        Qb + base + (size_t)(m0 + reg) * DH_);
                }
            } else if (!bxi) {
                size_t base = (((size_t)t * H_ + h) * NRG_ + rb) * DH_ + d;
#pragma unroll
                for (int reg = 0; reg < 4; ++reg) {
                    __builtin_nontemporal_store(vv[reg],
                        Kp + base + (size_t)(m0 + reg) * DH_);
                    __builtin_nontemporal_store(f2bf(vv[reg]),
                        Kb + base + (size_t)(m0 + reg) * DH_);
                }
            } else {
                size_t base = (((size_t)t * H_ + h) * NRG_ + rb) * DH_ + d;
#pragma unroll
                for (int reg = 0; reg < 4; ++reg)
                    __builtin_nontemporal_store(vv[reg],
                        Vp + base + (size_t)(m0 + reg) * DH_);
                // transposed bf16: 4 regs = 4 consecutive r -> one 8B store
                size_t tb = ((size_t)t * H_ + h) * DH_ * NRG_;
                unsigned long long u64 =
                    (unsigned long long)pk2(vv[0], vv[1]) |
                    ((unsigned long long)pk2(vv[2], vv[3]) << 32);
                __builtin_nontemporal_store(u64,
                    (unsigned long long*)(Vtb + tb + (size_t)d * NRG_ + rb + m0));
            }
        }
}

// ---------------------------------------------------------------------------
// gemm_wide (modes 3/0/5): BM=64, BN=256, 512 thr. A bf16 row-major, Bt NxK.
// ---------------------------------------------------------------------------
__global__ __launch_bounds__(512) void gemm_wide(
    const ushort* __restrict__ Ab, const ushort* __restrict__ Bt,
    const float* __restrict__ bias0, const float* __restrict__ bias1,
    const float* __restrict__ aux0, const ushort* __restrict__ residb,
    float* __restrict__ out0, ushort* __restrict__ out2,
    int N, int K, int mode) {
    __shared__ ushort smem[64 * 72 + 256 * 72];
    __shared__ float lnp[2][64][4];
    ushort (*As)[72] = (ushort(*)[72])smem;
    ushort (*Bs)[72] = (ushort(*)[72])(smem + 64 * 72);
    float (*Et)[68] = (float(*)[68])smem;

    int bxi = blockIdx.x, by = blockIdx.y;
    int bn = bxi * 256, bm = by * 64;

    int tid = threadIdx.x;
    int w = tid >> 6, lane = tid & 63;
    int wm = w >> 2, wn = w & 3;
    int l15 = lane & 15, l4 = lane >> 4;

    f32x4 acc[2][4];
#pragma unroll
    for (int i = 0; i < 2; ++i)
#pragma unroll
        for (int j = 0; j < 4; ++j)
#pragma unroll
            for (int r = 0; r < 4; ++r) acc[i][j][r] = 0.0f;

    for (int k0 = 0; k0 < K; k0 += 64) {
        {
            int row = tid >> 3, c8 = (tid & 7) * 8;
            *(bf16x8*)&As[row][c8] =
                *(const bf16x8*)(Ab + (size_t)(bm + row) * K + k0 + c8);
        }
#pragma unroll
        for (int it = 0; it < 4; ++it) {
            int li = tid + it * 512;
            int row = li >> 3, c8 = (li & 7) * 8;
            *(bf16x8*)&Bs[row][c8] =
                *(const bf16x8*)(Bt + (size_t)(bn + row) * K + k0 + c8);
        }
        __syncthreads();
#pragma unroll
        for (int kk = 0; kk < 2; ++kk) {
            bf16x8 af[2], bfr[4];
#pragma unroll
            for (int i = 0; i < 2; ++i)
                af[i] = *(const bf16x8*)&As[wm * 32 + i * 16 + l15][kk * 32 + l4 * 8];
#pragma unroll
            for (int j = 0; j < 4; ++j)
                bfr[j] = *(const bf16x8*)&Bs[wn * 64 + j * 16 + l15][kk * 32 + l4 * 8];
#pragma unroll
            for (int i = 0; i < 2; ++i)
#pragma unroll
                for (int j = 0; j < 4; ++j)
                    acc[i][j] = __builtin_amdgcn_mfma_f32_16x16x32_bf16(
                        af[i], bfr[j], acc[i][j], 0, 0, 0);
        }
        __syncthreads();
    }

    float v[2][4][4];
#pragma unroll
    for (int i = 0; i < 2; ++i)
#pragma unroll
        for (int j = 0; j < 4; ++j)
#pragma unroll
            for (int reg = 0; reg < 4; ++reg) {
                int nl = wn * 64 + j * 16 + l15;
                int rowl = wm * 32 + i * 16 + l4 * 4 + reg;
                float bs = (mode == 0) ? bias0[bn + nl] : bias0[nl];
                float x = fmaxf(acc[i][j][reg] + bs, 0.0f);
                if (mode == 3) x += bf2f(residb[(size_t)(bm + rowl) * 256 + nl]);
                v[i][j][reg] = x;
            }

    if (mode == 5) {
        float rs_[2][4], rq_[2][4];
#pragma unroll
        for (int i = 0; i < 2; ++i)
#pragma unroll
            for (int reg = 0; reg < 4; ++reg) {
                float s = 0.0f, q = 0.0f;
#pragma unroll
                for (int j = 0; j < 4; ++j) {
                    float x = v[i][j][reg];
                    s += x; q += x * x;
                }
#pragma unroll
                for (int off = 1; off < 16; off <<= 1) {
                    s += __shfl_xor(s, off);
                    q += __shfl_xor(q, off);
                }
                rs_[i][reg] = s; rq_[i][reg] = q;
            }
        if (l15 == 0) {
#pragma unroll
            for (int i = 0; i < 2; ++i)
#pragma unroll
                for (int reg = 0; reg < 4; ++reg) {
                    int row = wm * 32 + i * 16 + l4 * 4 + reg;
                    lnp[0][row][wn] = rs_[i][reg];
                    lnp[1][row][wn] = rq_[i][reg];
                }
        }
        __syncthreads();
#pragma unroll
        for (int i = 0; i < 2; ++i)
#pragma unroll
            for (int reg = 0; reg < 4; ++reg) {
                int row = wm * 32 + i * 16 + l4 * 4 + reg;
                float S1 = lnp[0][row][0] + lnp[0][row][1] + lnp[0][row][2] + lnp[0][row][3];
                float S2 = lnp[1][row][0] + lnp[1][row][1] + lnp[1][row][2] + lnp[1][row][3];
                float mean = S1 * (1.0f / 256.0f);
                float var = S2 * (1.0f / 256.0f) - mean * mean;
                float rstd = rsqrtf(var + 1e-5f);
#pragma unroll
                for (int j = 0; j < 4; ++j) {
                    int nl = wn * 64 + j * 16 + l15;
                    float z = (v[i][j][reg] - mean) * rstd * bias1[nl] + aux0[nl];
                    out0[(size_t)(bm + row) * 256 + nl] = z;
                }
            }
        return;
    }

#pragma unroll 1
    for (int jq = 0; jq < 4; ++jq) {
        __syncthreads();
        if (wn == jq) {
#pragma unroll
            for (int i = 0; i < 2; ++i)
#pragma unroll
                for (int j = 0; j < 4; ++j)
#pragma unroll
                    for (int reg = 0; reg < 4; ++reg)
                        Et[wm * 32 + i * 16 + l4 * 4 + reg][j * 16 + l15] = v[i][j][reg];
        }
        __syncthreads();
#pragma unroll
        for (int it = 0; it < 2; ++it) {
            int slot = it * 512 + tid;
            int row = slot >> 4, c4 = (slot & 15) * 4;
            uint2 u = make_uint2(pk2(Et[row][c4], Et[row][c4 + 1]),
                                 pk2(Et[row][c4 + 2], Et[row][c4 + 3]));
            *(uint2*)(out2 + (size_t)(bm + row) * N + bn + jq * 64 + c4) = u;
        }
    }
}

// ---------------------------------------------------------------------------
// Flash attention v4: one block per (t,h), 512 thr / 8 waves.
// ---------------------------------------------------------------------------
__global__ __launch_bounds__(512) void attn_flash(
    const ushort* __restrict__ Qb, const ushort* __restrict__ Kb,
    const ushort* __restrict__ Vtb, const unsigned* __restrict__ cm,
    ushort* __restrict__ Y1b) {
    int th = blockIdx.x;
    int t = th >> 2, h = th & 3;
    int tid = threadIdx.x;
    int w = tid >> 6, lane = tid & 63;
    int l15 = lane & 15, l4 = lane >> 4;

    __shared__ ushort Ks[2][64][72];
    __shared__ ushort Vts[2][64][72];
    __shared__ ushort Ps[128][72];
    __shared__ unsigned cmAll[128][33];

    bf16x8 qf[2];
#pragma unroll
    for (int kk = 0; kk < 2; ++kk)
        qf[kk] = *(const bf16x8*)(Qb + ((size_t)th * NA_ + w * 16 + l15) * DH_
                                  + kk * 32 + l4 * 8);

    {
        const uint4* src = (const uint4*)(cm + (size_t)t * NA_ * 32 + tid * 8);
        uint4 c0 = src[0], c1 = src[1];
        int a = tid >> 2, wd = (tid & 3) * 8;
        cmAll[a][wd + 0] = c0.x; cmAll[a][wd + 1] = c0.y;
        cmAll[a][wd + 2] = c0.z; cmAll[a][wd + 3] = c0.w;
        cmAll[a][wd + 4] = c1.x; cmAll[a][wd + 5] = c1.y;
        cmAll[a][wd + 6] = c1.z; cmAll[a][wd + 7] = c1.w;
    }

    int srow = tid >> 3, sc8 = (tid & 7) * 8;
    const ushort* Kbase = Kb + (size_t)th * NRG_ * DH_;
    const ushort* Vbase = Vtb + (size_t)th * DH_ * NRG_;
    bf16x8 kreg = *(const bf16x8*)(Kbase + (size_t)srow * DH_ + sc8);
    bf16x8 vreg = *(const bf16x8*)(Vbase + (size_t)srow * NRG_ + sc8);
    *(bf16x8*)&Ks[0][srow][sc8] = kreg;
    *(bf16x8*)&Vts[0][srow][sc8] = vreg;
    __syncthreads();

    f32x4 o[4];
    float rsum[4] = {0.0f, 0.0f, 0.0f, 0.0f};
#pragma unroll
    for (int ds = 0; ds < 4; ++ds)
#pragma unroll
        for (int r = 0; r < 4; ++r) o[ds][r] = 0.0f;

    for (int rt = 0; rt < 16; ++rt) {
        int cur = rt & 1;
        if (rt < 15) {
            int r0n = (rt + 1) * 64;
            kreg = *(const bf16x8*)(Kbase + (size_t)(r0n + srow) * DH_ + sc8);
            vreg = *(const bf16x8*)(Vbase + (size_t)srow * NRG_ + r0n + sc8);
        }

        f32x4 e[4];
#pragma unroll
        for (int rs = 0; rs < 4; ++rs) {
#pragma unroll
            for (int r = 0; r < 4; ++r) e[rs][r] = 0.0f;
#pragma unroll
            for (int kk = 0; kk < 2; ++kk) {
                bf16x8 kf = *(const bf16x8*)&Ks[cur][rs * 16 + l15][kk * 32 + l4 * 8];
                e[rs] = __builtin_amdgcn_mfma_f32_16x16x32_bf16(qf[kk], kf, e[rs], 0, 0, 0);
            }
        }

#pragma unroll
        for (int reg = 0; reg < 4; ++reg) {
            int a_loc = w * 16 + l4 * 4 + reg;
            unsigned w0 = cmAll[a_loc][rt * 2], w1 = cmAll[a_loc][rt * 2 + 1];
#pragma unroll
            for (int rs = 0; rs < 4; ++rs) {
                unsigned wd = (rs & 2) ? w1 : w0;
                int bit = (wd >> ((rs & 1) * 16 + l15)) & 1;
                float p = bit ? __expf(e[rs][reg]) : P_EPS;
                rsum[reg] += p;
                Ps[a_loc][rs * 16 + l15] = f2bf(p);
            }
        }

#pragma unroll
        for (int rc = 0; rc < 2; ++rc) {
            bf16x8 pa = *(const bf16x8*)&Ps[w * 16 + l15][rc * 32 + l4 * 8];
#pragma unroll
            for (int ds = 0; ds < 4; ++ds) {
                bf16x8 vf = *(const bf16x8*)&Vts[cur][ds * 16 + l15][rc * 32 + l4 * 8];
                o[ds] = __builtin_amdgcn_mfma_f32_16x16x32_bf16(pa, vf, o[ds], 0, 0, 0);
            }
        }

        if (rt < 15) {
            *(bf16x8*)&Ks[cur ^ 1][srow][sc8] = kreg;
            *(bf16x8*)&Vts[cur ^ 1][srow][sc8] = vreg;
            __syncthreads();
        }
    }

#pragma unroll
    for (int off = 1; off < 16; off <<= 1)
#pragma unroll
        for (int reg = 0; reg < 4; ++reg)
            rsum[reg] += __shfl_xor(rsum[reg], off);
    float rinv[4];
#pragma unroll
    for (int reg = 0; reg < 4; ++reg) rinv[reg] = 1.0f / rsum[reg];

#pragma unroll
    for (int ds = 0; ds < 4; ++ds)
#pragma unroll
        for (int reg = 0; reg < 4; ++reg) {
            int a_g = w * 16 + l4 * 4 + reg;
            int d = ds * 16 + l15;
            Y1b[((size_t)a_g * T_ + t) * D_ + h * DH_ + d] = f2bf(o[ds][reg] * rinv[reg]);
        }
}

// ---------------------------------------------------------------------------
extern "C" void kernel_launch(void* const* d_in, const int* in_sizes, int n_in,
                              void* d_out, int out_size, void* d_ws, size_t ws_size,
                              hipStream_t stream) {
    const float* agent   = (const float*)d_in[0];
    const float* rg      = (const float*)d_in[1];
    const float* ln_x_g  = (const float*)d_in[2];
    const float* ln_x_b  = (const float*)d_in[3];
    const float* wk      = (const float*)d_in[4];
    const float* bk      = (const float*)d_in[5];
    const float* wv      = (const float*)d_in[6];
    const float* bv      = (const float*)d_in[7];
    const float* wq      = (const float*)d_in[8];
    const float* bq      = (const float*)d_in[9];
    const float* q_scale = (const float*)d_in[10];
    const float* wy      = (const float*)d_in[11];
    const float* by      = (const float*)d_in[12];
    const float* wf1     = (const float*)d_in[13];
    const float* bf1     = (const float*)d_in[14];
    const float* wf2     = (const float*)d_in[15];
    const float* bf2     = (const float*)d_in[16];
    const float* ln_z_g  = (const float*)d_in[17];
    const float* ln_z_b  = (const float*)d_in[18];
    const int*   am      = (const int*)d_in[19];
    const int*   pm      = (const int*)d_in[20];
    const int*   vmk     = (const int*)d_in[21];

    float* Z  = (float*)d_out;
    float* Qp = Z + (size_t)NA_ * T_ * D_;
    float* Kp = Qp + (size_t)NA_ * T_ * D_;
    float* Vp = Kp + (size_t)NRG_ * T_ * D_;

    char* p = (char*)d_ws;
    ushort* agn_b = (ushort*)p;   p += (size_t)NA_ * T_ * D_ * 2;
    ushort* wkvt  = (ushort*)p;   p += (size_t)512 * 256 * 2;
    ushort* wqt   = (ushort*)p;   p += (size_t)256 * 256 * 2;
    ushort* wyt   = (ushort*)p;   p += (size_t)256 * 256 * 2;
    ushort* wf1t  = (ushort*)p;   p += (size_t)1024 * 256 * 2;
    ushort* wf2t  = (ushort*)p;   p += (size_t)256 * 1024 * 2;
    unsigned* cm  = (unsigned*)p; p += (size_t)T_ * NA_ * 32 * 4;
    ushort* Kb    = (ushort*)p;   p += (size_t)T_ * H_ * NRG_ * DH_ * 2;
    ushort* Vtb   = (ushort*)p;   p += (size_t)T_ * H_ * NRG_ * DH_ * 2;
    ushort* Qb    = (ushort*)p;   p += (size_t)T_ * H_ * NA_ * DH_ * 2;
    ushort* Y1b   = (ushort*)p;   p += (size_t)NA_ * T_ * D_ * 2;
    ushort* Sb    = (ushort*)p;   p += (size_t)NA_ * T_ * D_ * 2;
    ushort* F1b   = (ushort*)p;   p += (size_t)NA_ * T_ * D_ * KEXP_ * 2;

    prep_all<<<dim3(LN_BLOCKS + PM_BLOCKS + PW_BLOCKS), dim3(256), 0, stream>>>(
        agent, ln_x_g, ln_x_b, am, pm, vmk,
        wk, wv, wq, wy, wf1, wf2,
        agn_b, cm, wkvt, wqt, wyt, wf1t, wf2t);

    gemm_kvq<<<dim3(KV_BLOCKS + T_ * 2), dim3(512), 0, stream>>>(
        rg, agn_b, ln_x_g, ln_x_b, wkvt, wqt, bk, bv, bq, q_scale,
        Kp, Vp, Qp, Kb, Vtb, Qb);

    attn_flash<<<dim3(T_ * H_), dim3(512), 0, stream>>>(Qb, Kb, Vtb, cm, Y1b);

    // S = relu(Y1 @ wy + by) + agent_n
    gemm_wide<<<dim3(1, NA_ * T_ / 64), dim3(512), 0, stream>>>(
        Y1b, wyt, by, nullptr, nullptr, agn_b,
        nullptr, Sb, 256, 256, 3);

    // F1 = relu(S @ wf1 + bf1)
    gemm_wide<<<dim3(4, NA_ * T_ / 64), dim3(512), 0, stream>>>(
        Sb, wf1t, bf1, nullptr, nullptr, nullptr,
        nullptr, F1b, 1024, 256, 0);

    // Z = ln(relu(F1 @ wf2 + bf2))
    gemm_wide<<<dim3(1, NA_ * T_ / 64), dim3(512), 0, stream>>>(
        F1b, wf2t, bf2, ln_z_g, ln_z_b, nullptr,
        Z, nullptr, 256, 1024, 5);
}

// Round 18
// 241.877 us; speedup vs baseline: 1.2282x; 1.2282x over previous
//
#include <hip/hip_runtime.h>

#define T_   91
#define D_   256
#define H_   4
#define DH_  64
#define NA_  128
#define NRG_ 1024
#define KEXP_ 4

typedef float f32x4 __attribute__((ext_vector_type(4)));
typedef short bf16x8 __attribute__((ext_vector_type(8)));

static constexpr float P_EPS = 1.3877787807814457e-17f;  // 2^-56, exact in bf16

__device__ inline ushort f2bf(float f) {
    union { float f; unsigned u; } v; v.f = f;
    unsigned r = (v.u + 0x7fffu + ((v.u >> 16) & 1u)) >> 16;
    return (ushort)r;
}
__device__ inline unsigned pk2(float a, float b) {
    return (unsigned)f2bf(a) | ((unsigned)f2bf(b) << 16);
}
__device__ inline float bf2f(ushort b) {
    union { unsigned u; float f; } v; v.u = ((unsigned)b) << 16;
    return v.f;
}

#define LN_BLOCKS 2912    // NA*T/4 (agent rows only)
#define PM_BLOCKS 2912    // T*NA/4
#define PW_BLOCKS 3072    // 786432/256
#define KV_BLOCKS 2912    // 1456 tiles * 2 (K, V)

// ---------------------------------------------------------------------------
// prep_all: [0,LN) agent LN (wave/row) | [LN,LN+PM) pack_mask | rest prep_w
// ---------------------------------------------------------------------------
__global__ __launch_bounds__(256) void prep_all(
    const float* __restrict__ agent,
    const float* __restrict__ g, const float* __restrict__ b,
    const int* __restrict__ am, const int* __restrict__ pm,
    const int* __restrict__ vmk,
    const float* __restrict__ wk, const float* __restrict__ wv,
    const float* __restrict__ wq, const float* __restrict__ wy,
    const float* __restrict__ wf1, const float* __restrict__ wf2,
    ushort* __restrict__ agn, unsigned* __restrict__ cm,
    ushort* __restrict__ wkvt, ushort* __restrict__ wqt,
    ushort* __restrict__ wyt, ushort* __restrict__ wf1t,
    ushort* __restrict__ wf2t) {
    __shared__ int pmS[NRG_];
    int bid = blockIdx.x;
    if (bid < LN_BLOCKS) {
        int row = bid * 4 + (threadIdx.x >> 6);
        int lane = threadIdx.x & 63;
        f32x4 x = *(const f32x4*)(agent + (size_t)row * D_ + lane * 4);
        float s1 = x[0] + x[1] + x[2] + x[3];
        float s2 = x[0] * x[0] + x[1] * x[1] + x[2] * x[2] + x[3] * x[3];
#pragma unroll
        for (int off = 1; off < 64; off <<= 1) {
            s1 += __shfl_xor(s1, off);
            s2 += __shfl_xor(s2, off);
        }
        float mean = s1 * (1.0f / 256.0f);
        float var = s2 * (1.0f / 256.0f) - mean * mean;
        float rstd = rsqrtf(var + 1e-5f);
        f32x4 gv = *(const f32x4*)(g + lane * 4);
        f32x4 bv = *(const f32x4*)(b + lane * 4);
        float y0 = (x[0] - mean) * rstd * gv[0] + bv[0];
        float y1 = (x[1] - mean) * rstd * gv[1] + bv[1];
        float y2 = (x[2] - mean) * rstd * gv[2] + bv[2];
        float y3 = (x[3] - mean) * rstd * gv[3] + bv[3];
        *(uint2*)(agn + (size_t)row * D_ + lane * 4) =
            make_uint2(pk2(y0, y1), pk2(y2, y3));
    } else if (bid < LN_BLOCKS + PM_BLOCKS) {
        int base = (bid - LN_BLOCKS) * 4;
        int t = base / NA_;
        int w = threadIdx.x >> 6, lane = threadIdx.x & 63;
#pragma unroll
        for (int i = 0; i < 4; ++i)
            pmS[threadIdx.x + i * 256] = pm[(size_t)t * NRG_ + threadIdx.x + i * 256];
        __syncthreads();
        int idx = base + w;
        int a = idx & (NA_ - 1);
        int valid = vmk[t * NA_ + a];
        const int* amrow = am + (size_t)idx * NRG_;
#pragma unroll
        for (int c = 0; c < 16; ++c) {
            int r = c * 64 + lane;
            bool bit = valid && amrow[r] && pmS[r];
            unsigned long long msk = __ballot(bit);
            if (lane == 0) {
                cm[(size_t)idx * 32 + c * 2]     = (unsigned)msk;
                cm[(size_t)idx * 32 + c * 2 + 1] = (unsigned)(msk >> 32);
            }
        }
    } else {
        int idx = (bid - LN_BLOCKS - PM_BLOCKS) * 256 + threadIdx.x;
        if (idx < 131072) {
            const float* W = (idx < 65536) ? wk : wv;
            int li = idx & 65535;
            int n = li >> 8, k = li & 255;
            wkvt[idx] = f2bf(W[(size_t)k * 256 + n]);
        } else if (idx < 196608) {
            int li = idx - 131072;
            int n = li >> 8, k = li & 255;
            wqt[li] = f2bf(wq[(size_t)k * 256 + n]);
        } else if (idx < 262144) {
            int li = idx - 196608;
            int n = li >> 8, k = li & 255;
            wyt[li] = f2bf(wy[(size_t)k * 256 + n]);
        } else if (idx < 524288) {
            int li = idx - 262144;
            int n = li >> 8, k = li & 255;
            wf1t[li] = f2bf(wf1[(size_t)k * 1024 + n]);
        } else {
            int li = idx - 524288;
            int n = li >> 10, k = li & 1023;
            wf2t[li] = f2bf(wf2[(size_t)k * 256 + n]);
        }
    }
}

// ---------------------------------------------------------------------------
// KV + Q projection (round-11 best): BM=64, BN=256, 512 thr, one-pass full-A
// LN staging, LDS B-staging, direct reg->global epilogue (no barriers).
// bid < KV_BLOCKS: XCD-paired (K and V of one tile differ by 8 -> same XCD).
// bid >= KV_BLOCKS: Q from agn: Qp f32 (t,h,a,d) + Qb bf16 (x0.5, x qscale).
// ---------------------------------------------------------------------------
__global__ __launch_bounds__(512) void gemm_kvq(
    const float* __restrict__ rgf, const ushort* __restrict__ agn,
    const float* __restrict__ lng, const float* __restrict__ lnb,
    const ushort* __restrict__ wkvt, const ushort* __restrict__ wqt,
    const float* __restrict__ bk, const float* __restrict__ bv,
    const float* __restrict__ bq, const float* __restrict__ qs,
    float* __restrict__ Kp, float* __restrict__ Vp, float* __restrict__ Qp,
    ushort* __restrict__ Kb, ushort* __restrict__ Vtb, ushort* __restrict__ Qb) {
    __shared__ ushort Asf[64][264];               // 33.8 KB (full 64x256 A tile)
    __shared__ ushort Bs[256][72];                // 36.9 KB

    int bid = blockIdx.x;
    bool isQ = bid >= KV_BLOCKS;
    int bxi = 0, t, rb = 0, a0 = 0;
    if (!isQ) {
        int sub = bid & 15, pid = bid >> 4;
        bxi = sub >> 3;
        int by = pid * 8 + (sub & 7);             // K/V pair differs by 8 in bid
        t = by >> 4; rb = (by & 15) << 6;
    } else {
        int qid = bid - KV_BLOCKS;                // 0..181
        t = qid >> 1; a0 = (qid & 1) << 6;
    }
    const ushort* Bt = isQ ? wqt : (wkvt + (size_t)(bxi << 8) * 256);

    int tid = threadIdx.x;
    int w = tid >> 6, lane = tid & 63;
    int wm = w >> 2, wn = w & 3;
    int l15 = lane & 15, l4 = lane >> 4;

    // ---- A tile into Asf (LN fused for rg path) ----
    if (!isQ) {
        int row = tid >> 3, l8 = tid & 7;
        const float* ap = rgf + ((size_t)(rb + row) * T_ + t) * 256;
        f32x4 xr[8];
#pragma unroll
        for (int c = 0; c < 8; ++c) xr[c] = *(const f32x4*)(ap + l8 * 4 + c * 32);
        float s1 = 0.0f, s2 = 0.0f;
#pragma unroll
        for (int c = 0; c < 8; ++c)
#pragma unroll
            for (int r = 0; r < 4; ++r) { s1 += xr[c][r]; s2 += xr[c][r] * xr[c][r]; }
#pragma unroll
        for (int off = 1; off < 8; off <<= 1) {
            s1 += __shfl_xor(s1, off);
            s2 += __shfl_xor(s2, off);
        }
        float mean = s1 * (1.0f / 256.0f);
        float var = s2 * (1.0f / 256.0f) - mean * mean;
        float rstd = rsqrtf(var + 1e-5f);
#pragma unroll
        for (int c = 0; c < 8; ++c) {
            int col = l8 * 4 + c * 32;
            f32x4 g4 = *(const f32x4*)(lng + col);
            f32x4 b4 = *(const f32x4*)(lnb + col);
            float y0 = (xr[c][0] - mean) * rstd * g4[0] + b4[0];
            float y1 = (xr[c][1] - mean) * rstd * g4[1] + b4[1];
            float y2 = (xr[c][2] - mean) * rstd * g4[2] + b4[2];
            float y3 = (xr[c][3] - mean) * rstd * g4[3] + b4[3];
            *(uint2*)&Asf[row][col] = make_uint2(pk2(y0, y1), pk2(y2, y3));
        }
    } else {
#pragma unroll
        for (int i2 = 0; i2 < 4; ++i2) {
            int chunk = tid + i2 * 512;
            int row = chunk >> 5, c8 = (chunk & 31) * 8;
            *(bf16x8*)&Asf[row][c8] =
                *(const bf16x8*)(agn + ((size_t)(a0 + row) * T_ + t) * 256 + c8);
        }
    }

    f32x4 acc[2][4];
#pragma unroll
    for (int i = 0; i < 2; ++i)
#pragma unroll
        for (int j = 0; j < 4; ++j)
#pragma unroll
            for (int r = 0; r < 4; ++r) acc[i][j][r] = 0.0f;

    for (int k0 = 0; k0 < 256; k0 += 64) {
#pragma unroll
        for (int it = 0; it < 4; ++it) {
            int li = tid + it * 512;
            int row = li >> 3, c8 = (li & 7) * 8;
            *(bf16x8*)&Bs[row][c8] =
                *(const bf16x8*)(Bt + (size_t)row * 256 + k0 + c8);
        }
        __syncthreads();
#pragma unroll
        for (int kk = 0; kk < 2; ++kk) {
            bf16x8 af[2], bfr[4];
#pragma unroll
            for (int i = 0; i < 2; ++i)
                af[i] = *(const bf16x8*)&Asf[wm * 32 + i * 16 + l15][k0 + kk * 32 + l4 * 8];
#pragma unroll
            for (int j = 0; j < 4; ++j)
                bfr[j] = *(const bf16x8*)&Bs[wn * 64 + j * 16 + l15][kk * 32 + l4 * 8];
#pragma unroll
            for (int i = 0; i < 2; ++i)
#pragma unroll
                for (int j = 0; j < 4; ++j)
                    acc[i][j] = __builtin_amdgcn_mfma_f32_16x16x32_bf16(
                        af[i], bfr[j], acc[i][j], 0, 0, 0);
        }
        __syncthreads();
    }

    // ---- direct epilogue: no barriers, no LDS staging ----
#pragma unroll
    for (int i = 0; i < 2; ++i)
#pragma unroll
        for (int j = 0; j < 4; ++j) {
            int n = wn * 64 + j * 16 + l15;        // 0..255
            int h = n >> 6, d = n & 63;
            int m0 = wm * 32 + i * 16 + l4 * 4;    // tile row of reg 0
            float vv[4];
#pragma unroll
            for (int reg = 0; reg < 4; ++reg) {
                float bs = isQ ? bq[n] : (bxi ? bv[n] : bk[n]);
                float x = fmaxf(acc[i][j][reg] + bs, 0.0f);
                if (isQ) x *= qs[d];
                vv[reg] = x;
            }
            if (isQ) {
                size_t base = (((size_t)t * H_ + h) * NA_ + a0) * DH_ + d;
#pragma unroll
                for (int reg = 0; reg < 4; ++reg) {
                    Qp[base + (size_t)(m0 + reg) * DH_] = vv[reg];
                    Qb[base + (size_t)(m0 + reg) * DH_] = f2bf(vv[reg] * 0.5f);
                }
            } else if (!bxi) {
                size_t base = (((size_t)t * H_ + h) * NRG_ + rb) * DH_ + d;
#pragma unroll
                for (int reg = 0; reg < 4; ++reg) {
                    Kp[base + (size_t)(m0 + reg) * DH_] = vv[reg];
                    Kb[base + (size_t)(m0 + reg) * DH_] = f2bf(vv[reg]);
                }
            } else {
                size_t base = (((size_t)t * H_ + h) * NRG_ + rb) * DH_ + d;
#pragma unroll
                for (int reg = 0; reg < 4; ++reg)
                    Vp[base + (size_t)(m0 + reg) * DH_] = vv[reg];
                // transposed bf16: 4 regs = 4 consecutive r -> one uint2
                size_t tb = ((size_t)t * H_ + h) * DH_ * NRG_;
                *(uint2*)(Vtb + tb + (size_t)d * NRG_ + rb + m0) =
                    make_uint2(pk2(vv[0], vv[1]), pk2(vv[2], vv[3]));
            }
        }
}

// ---------------------------------------------------------------------------
// gemm_wide (modes 3/0/5): BM=64, BN=256, 512 thr. A bf16 row-major, Bt NxK.
// ---------------------------------------------------------------------------
__global__ __launch_bounds__(512) void gemm_wide(
    const ushort* __restrict__ Ab, const ushort* __restrict__ Bt,
    const float* __restrict__ bias0, const float* __restrict__ bias1,
    const float* __restrict__ aux0, const ushort* __restrict__ residb,
    float* __restrict__ out0, ushort* __restrict__ out2,
    int N, int K, int mode) {
    __shared__ ushort smem[64 * 72 + 256 * 72];
    __shared__ float lnp[2][64][4];
    ushort (*As)[72] = (ushort(*)[72])smem;
    ushort (*Bs)[72] = (ushort(*)[72])(smem + 64 * 72);
    float (*Et)[68] = (float(*)[68])smem;

    int bxi = blockIdx.x, by = blockIdx.y;
    int bn = bxi * 256, bm = by * 64;

    int tid = threadIdx.x;
    int w = tid >> 6, lane = tid & 63;
    int wm = w >> 2, wn = w & 3;
    int l15 = lane & 15, l4 = lane >> 4;

    f32x4 acc[2][4];
#pragma unroll
    for (int i = 0; i < 2; ++i)
#pragma unroll
        for (int j = 0; j < 4; ++j)
#pragma unroll
            for (int r = 0; r < 4; ++r) acc[i][j][r] = 0.0f;

    for (int k0 = 0; k0 < K; k0 += 64) {
        {
            int row = tid >> 3, c8 = (tid & 7) * 8;
            *(bf16x8*)&As[row][c8] =
                *(const bf16x8*)(Ab + (size_t)(bm + row) * K + k0 + c8);
        }
#pragma unroll
        for (int it = 0; it < 4; ++it) {
            int li = tid + it * 512;
            int row = li >> 3, c8 = (li & 7) * 8;
            *(bf16x8*)&Bs[row][c8] =
                *(const bf16x8*)(Bt + (size_t)(bn + row) * K + k0 + c8);
        }
        __syncthreads();
#pragma unroll
        for (int kk = 0; kk < 2; ++kk) {
            bf16x8 af[2], bfr[4];
#pragma unroll
            for (int i = 0; i < 2; ++i)
                af[i] = *(const bf16x8*)&As[wm * 32 + i * 16 + l15][kk * 32 + l4 * 8];
#pragma unroll
            for (int j = 0; j < 4; ++j)
                bfr[j] = *(const bf16x8*)&Bs[wn * 64 + j * 16 + l15][kk * 32 + l4 * 8];
#pragma unroll
            for (int i = 0; i < 2; ++i)
#pragma unroll
                for (int j = 0; j < 4; ++j)
                    acc[i][j] = __builtin_amdgcn_mfma_f32_16x16x32_bf16(
                        af[i], bfr[j], acc[i][j], 0, 0, 0);
        }
        __syncthreads();
    }

    float v[2][4][4];
#pragma unroll
    for (int i = 0; i < 2; ++i)
#pragma unroll
        for (int j = 0; j < 4; ++j)
#pragma unroll
            for (int reg = 0; reg < 4; ++reg) {
                int nl = wn * 64 + j * 16 + l15;
                int rowl = wm * 32 + i * 16 + l4 * 4 + reg;
                float bs = (mode == 0) ? bias0[bn + nl] : bias0[nl];
                float x = fmaxf(acc[i][j][reg] + bs, 0.0f);
                if (mode == 3) x += bf2f(residb[(size_t)(bm + rowl) * 256 + nl]);
                v[i][j][reg] = x;
            }

    if (mode == 5) {
        float rs_[2][4], rq_[2][4];
#pragma unroll
        for (int i = 0; i < 2; ++i)
#pragma unroll
            for (int reg = 0; reg < 4; ++reg) {
                float s = 0.0f, q = 0.0f;
#pragma unroll
                for (int j = 0; j < 4; ++j) {
                    float x = v[i][j][reg];
                    s += x; q += x * x;
                }
#pragma unroll
                for (int off = 1; off < 16; off <<= 1) {
                    s += __shfl_xor(s, off);
                    q += __shfl_xor(q, off);
                }
                rs_[i][reg] = s; rq_[i][reg] = q;
            }
        if (l15 == 0) {
#pragma unroll
            for (int i = 0; i < 2; ++i)
#pragma unroll
                for (int reg = 0; reg < 4; ++reg) {
                    int row = wm * 32 + i * 16 + l4 * 4 + reg;
                    lnp[0][row][wn] = rs_[i][reg];
                    lnp[1][row][wn] = rq_[i][reg];
                }
        }
        __syncthreads();
#pragma unroll
        for (int i = 0; i < 2; ++i)
#pragma unroll
            for (int reg = 0; reg < 4; ++reg) {
                int row = wm * 32 + i * 16 + l4 * 4 + reg;
                float S1 = lnp[0][row][0] + lnp[0][row][1] + lnp[0][row][2] + lnp[0][row][3];
                float S2 = lnp[1][row][0] + lnp[1][row][1] + lnp[1][row][2] + lnp[1][row][3];
                float mean = S1 * (1.0f / 256.0f);
                float var = S2 * (1.0f / 256.0f) - mean * mean;
                float rstd = rsqrtf(var + 1e-5f);
#pragma unroll
                for (int j = 0; j < 4; ++j) {
                    int nl = wn * 64 + j * 16 + l15;
                    float z = (v[i][j][reg] - mean) * rstd * bias1[nl] + aux0[nl];
                    out0[(size_t)(bm + row) * 256 + nl] = z;
                }
            }
        return;
    }

#pragma unroll 1
    for (int jq = 0; jq < 4; ++jq) {
        __syncthreads();
        if (wn == jq) {
#pragma unroll
            for (int i = 0; i < 2; ++i)
#pragma unroll
                for (int j = 0; j < 4; ++j)
#pragma unroll
                    for (int reg = 0; reg < 4; ++reg)
                        Et[wm * 32 + i * 16 + l4 * 4 + reg][j * 16 + l15] = v[i][j][reg];
        }
        __syncthreads();
#pragma unroll
        for (int it = 0; it < 2; ++it) {
            int slot = it * 512 + tid;
            int row = slot >> 4, c4 = (slot & 15) * 4;
            uint2 u = make_uint2(pk2(Et[row][c4], Et[row][c4 + 1]),
                                 pk2(Et[row][c4 + 2], Et[row][c4 + 3]));
            *(uint2*)(out2 + (size_t)(bm + row) * N + bn + jq * 64 + c4) = u;
        }
    }
}

// ---------------------------------------------------------------------------
// Flash attention v4: one block per (t,h), 512 thr / 8 waves.
// Double-buffered K/V staging, register prefetch; mask bits in LDS once.
// One barrier per iteration. No online max (Q,K >= 0); masked -> P_EPS.
// ---------------------------------------------------------------------------
__global__ __launch_bounds__(512) void attn_flash(
    const ushort* __restrict__ Qb, const ushort* __restrict__ Kb,
    const ushort* __restrict__ Vtb, const unsigned* __restrict__ cm,
    ushort* __restrict__ Y1b) {
    int th = blockIdx.x;
    int t = th >> 2, h = th & 3;
    int tid = threadIdx.x;
    int w = tid >> 6, lane = tid & 63;
    int l15 = lane & 15, l4 = lane >> 4;

    __shared__ ushort Ks[2][64][72];
    __shared__ ushort Vts[2][64][72];
    __shared__ ushort Ps[128][72];
    __shared__ unsigned cmAll[128][33];

    bf16x8 qf[2];
#pragma unroll
    for (int kk = 0; kk < 2; ++kk)
        qf[kk] = *(const bf16x8*)(Qb + ((size_t)th * NA_ + w * 16 + l15) * DH_
                                  + kk * 32 + l4 * 8);

    {
        const uint4* src = (const uint4*)(cm + (size_t)t * NA_ * 32 + tid * 8);
        uint4 c0 = src[0], c1 = src[1];
        int a = tid >> 2, wd = (tid & 3) * 8;
        cmAll[a][wd + 0] = c0.x; cmAll[a][wd + 1] = c0.y;
        cmAll[a][wd + 2] = c0.z; cmAll[a][wd + 3] = c0.w;
        cmAll[a][wd + 4] = c1.x; cmAll[a][wd + 5] = c1.y;
        cmAll[a][wd + 6] = c1.z; cmAll[a][wd + 7] = c1.w;
    }

    int srow = tid >> 3, sc8 = (tid & 7) * 8;
    const ushort* Kbase = Kb + (size_t)th * NRG_ * DH_;
    const ushort* Vbase = Vtb + (size_t)th * DH_ * NRG_;
    bf16x8 kreg = *(const bf16x8*)(Kbase + (size_t)srow * DH_ + sc8);
    bf16x8 vreg = *(const bf16x8*)(Vbase + (size_t)srow * NRG_ + sc8);
    *(bf16x8*)&Ks[0][srow][sc8] = kreg;
    *(bf16x8*)&Vts[0][srow][sc8] = vreg;
    __syncthreads();

    f32x4 o[4];
    float rsum[4] = {0.0f, 0.0f, 0.0f, 0.0f};
#pragma unroll
    for (int ds = 0; ds < 4; ++ds)
#pragma unroll
        for (int r = 0; r < 4; ++r) o[ds][r] = 0.0f;

    for (int rt = 0; rt < 16; ++rt) {
        int cur = rt & 1;
        if (rt < 15) {
            int r0n = (rt + 1) * 64;
            kreg = *(const bf16x8*)(Kbase + (size_t)(r0n + srow) * DH_ + sc8);
            vreg = *(const bf16x8*)(Vbase + (size_t)srow * NRG_ + r0n + sc8);
        }

        f32x4 e[4];
#pragma unroll
        for (int rs = 0; rs < 4; ++rs) {
#pragma unroll
            for (int r = 0; r < 4; ++r) e[rs][r] = 0.0f;
#pragma unroll
            for (int kk = 0; kk < 2; ++kk) {
                bf16x8 kf = *(const bf16x8*)&Ks[cur][rs * 16 + l15][kk * 32 + l4 * 8];
                e[rs] = __builtin_amdgcn_mfma_f32_16x16x32_bf16(qf[kk], kf, e[rs], 0, 0, 0);
            }
        }

#pragma unroll
        for (int reg = 0; reg < 4; ++reg) {
            int a_loc = w * 16 + l4 * 4 + reg;
            unsigned w0 = cmAll[a_loc][rt * 2], w1 = cmAll[a_loc][rt * 2 + 1];
#pragma unroll
            for (int rs = 0; rs < 4; ++rs) {
                unsigned wd = (rs & 2) ? w1 : w0;
                int bit = (wd >> ((rs & 1) * 16 + l15)) & 1;
                float p = bit ? __expf(e[rs][reg]) : P_EPS;
                rsum[reg] += p;
                Ps[a_loc][rs * 16 + l15] = f2bf(p);
            }
        }

#pragma unroll
        for (int rc = 0; rc < 2; ++rc) {
            bf16x8 pa = *(const bf16x8*)&Ps[w * 16 + l15][rc * 32 + l4 * 8];
#pragma unroll
            for (int ds = 0; ds < 4; ++ds) {
                bf16x8 vf = *(const bf16x8*)&Vts[cur][ds * 16 + l15][rc * 32 + l4 * 8];
                o[ds] = __builtin_amdgcn_mfma_f32_16x16x32_bf16(pa, vf, o[ds], 0, 0, 0);
            }
        }

        if (rt < 15) {
            *(bf16x8*)&Ks[cur ^ 1][srow][sc8] = kreg;
            *(bf16x8*)&Vts[cur ^ 1][srow][sc8] = vreg;
            __syncthreads();
        }
    }

#pragma unroll
    for (int off = 1; off < 16; off <<= 1)
#pragma unroll
        for (int reg = 0; reg < 4; ++reg)
            rsum[reg] += __shfl_xor(rsum[reg], off);
    float rinv[4];
#pragma unroll
    for (int reg = 0; reg < 4; ++reg) rinv[reg] = 1.0f / rsum[reg];

#pragma unroll
    for (int ds = 0; ds < 4; ++ds)
#pragma unroll
        for (int reg = 0; reg < 4; ++reg) {
            int a_g = w * 16 + l4 * 4 + reg;
            int d = ds * 16 + l15;
            Y1b[((size_t)a_g * T_ + t) * D_ + h * DH_ + d] = f2bf(o[ds][reg] * rinv[reg]);
        }
}

// ---------------------------------------------------------------------------
extern "C" void kernel_launch(void* const* d_in, const int* in_sizes, int n_in,
                              void* d_out, int out_size, void* d_ws, size_t ws_size,
                              hipStream_t stream) {
    const float* agent   = (const float*)d_in[0];
    const float* rg      = (const float*)d_in[1];
    const float* ln_x_g  = (const float*)d_in[2];
    const float* ln_x_b  = (const float*)d_in[3];
    const float* wk      = (const float*)d_in[4];
    const float* bk      = (const float*)d_in[5];
    const float* wv      = (const float*)d_in[6];
    const float* bv      = (const float*)d_in[7];
    const float* wq      = (const float*)d_in[8];
    const float* bq      = (const float*)d_in[9];
    const float* q_scale = (const float*)d_in[10];
    const float* wy      = (const float*)d_in[11];
    const float* by      = (const float*)d_in[12];
    const float* wf1     = (const float*)d_in[13];
    const float* bf1     = (const float*)d_in[14];
    const float* wf2     = (const float*)d_in[15];
    const float* bf2     = (const float*)d_in[16];
    const float* ln_z_g  = (const float*)d_in[17];
    const float* ln_z_b  = (const float*)d_in[18];
    const int*   am      = (const int*)d_in[19];
    const int*   pm      = (const int*)d_in[20];
    const int*   vmk     = (const int*)d_in[21];

    float* Z  = (float*)d_out;
    float* Qp = Z + (size_t)NA_ * T_ * D_;
    float* Kp = Qp + (size_t)NA_ * T_ * D_;
    float* Vp = Kp + (size_t)NRG_ * T_ * D_;

    char* p = (char*)d_ws;
    ushort* agn_b = (ushort*)p;   p += (size_t)NA_ * T_ * D_ * 2;
    ushort* wkvt  = (ushort*)p;   p += (size_t)512 * 256 * 2;
    ushort* wqt   = (ushort*)p;   p += (size_t)256 * 256 * 2;
    ushort* wyt   = (ushort*)p;   p += (size_t)256 * 256 * 2;
    ushort* wf1t  = (ushort*)p;   p += (size_t)1024 * 256 * 2;
    ushort* wf2t  = (ushort*)p;   p += (size_t)256 * 1024 * 2;
    unsigned* cm  = (unsigned*)p; p += (size_t)T_ * NA_ * 32 * 4;
    ushort* Kb    = (ushort*)p;   p += (size_t)T_ * H_ * NRG_ * DH_ * 2;
    ushort* Vtb   = (ushort*)p;   p += (size_t)T_ * H_ * NRG_ * DH_ * 2;
    ushort* Qb    = (ushort*)p;   p += (size_t)T_ * H_ * NA_ * DH_ * 2;
    ushort* Y1b   = (ushort*)p;   p += (size_t)NA_ * T_ * D_ * 2;
    ushort* Sb    = (ushort*)p;   p += (size_t)NA_ * T_ * D_ * 2;
    ushort* F1b   = (ushort*)p;   p += (size_t)NA_ * T_ * D_ * KEXP_ * 2;

    prep_all<<<dim3(LN_BLOCKS + PM_BLOCKS + PW_BLOCKS), dim3(256), 0, stream>>>(
        agent, ln_x_g, ln_x_b, am, pm, vmk,
        wk, wv, wq, wy, wf1, wf2,
        agn_b, cm, wkvt, wqt, wyt, wf1t, wf2t);

    gemm_kvq<<<dim3(KV_BLOCKS + T_ * 2), dim3(512), 0, stream>>>(
        rg, agn_b, ln_x_g, ln_x_b, wkvt, wqt, bk, bv, bq, q_scale,
        Kp, Vp, Qp, Kb, Vtb, Qb);

    attn_flash<<<dim3(T_ * H_), dim3(512), 0, stream>>>(Qb, Kb, Vtb, cm, Y1b);

    // S = relu(Y1 @ wy + by) + agent_n
    gemm_wide<<<dim3(1, NA_ * T_ / 64), dim3(512), 0, stream>>>(
        Y1b, wyt, by, nullptr, nullptr, agn_b,
        nullptr, Sb, 256, 256, 3);

    // F1 = relu(S @ wf1 + bf1)
    gemm_wide<<<dim3(4, NA_ * T_ / 64), dim3(512), 0, stream>>>(
        Sb, wf1t, bf1, nullptr, nullptr, nullptr,
        nullptr, F1b, 1024, 256, 0);

    // Z = ln(relu(F1 @ wf2 + bf2))
    gemm_wide<<<dim3(1, NA_ * T_ / 64), dim3(512), 0, stream>>>(
        F1b, wf2t, bf2, ln_z_g, ln_z_b, nullptr,
        Z, nullptr, 256, 1024, 5);
}